// Round 7
// baseline (135.704 us; speedup 1.0000x reference)
//
#include <hip/hip_runtime.h>
#include <hip/hip_bf16.h>
#include <math.h>
#include <stdint.h>

#define BATCH 2
#define NH 12
#define SEQ 2048
#define HD 64
#define TQ 64
#define TKK 128
#define NHEADS (BATCH*NH)
#define NITK (SEQ / TKK)

typedef short bf16x8 __attribute__((ext_vector_type(8)));
typedef float f32x4 __attribute__((ext_vector_type(4)));
typedef float f32x16 __attribute__((ext_vector_type(16)));
typedef unsigned short us4_t __attribute__((ext_vector_type(4)));
typedef unsigned short us8_t __attribute__((ext_vector_type(8)));

#if __has_builtin(__builtin_amdgcn_exp2f)
#define EXP2F(x) __builtin_amdgcn_exp2f(x)
#else
#define EXP2F(x) exp2f(x)
#endif

static __device__ __forceinline__ unsigned short f2bf(float f) {
    unsigned int u = __float_as_uint(f);
    u += 0x7fffu + ((u >> 16) & 1u);   // RTNE
    return (unsigned short)(u >> 16);
}

static __device__ __forceinline__ unsigned int pack2bf(float a, float b) {
    __hip_bfloat162 v = __float22bfloat162_rn(float2{a, b});
    return *(unsigned int*)&v;
}

// 64x64-bf16 tile (Q staging): conflict-free, 16B-aligned positions
static __device__ __forceinline__ int tile_off(int r, int c) {   // shorts, c 0..7
    int rp  = r >> 1;
    int pos = (((r & 1) << 3) | c) ^ (rp & 15);
    return rp * 128 + pos * 8;
}
// 64x32-bf16 tile (wave-private P): writes 2-way (free), b128 reads at minimum
static __device__ __forceinline__ int poff32(int r, int c) {     // shorts, c 0..3
    int rp  = r >> 1;
    int pos = (((r & 1) << 2) | c) ^ (rp & 7);
    return rp * 64 + pos * 8;
}

// ---- pre-pass: K -> bf16 (dense), V -> bf16 transposed [bh][d][s] ----
__global__ __launch_bounds__(256)
void prep_kv(const float* __restrict__ K, const float* __restrict__ V,
             unsigned short* __restrict__ Kb, unsigned short* __restrict__ Vtb) {
    __shared__ unsigned short T[64][66];
    const int bh = blockIdx.x >> 5;
    const int s0 = (blockIdx.x & 31) * 64;
    const int tid = threadIdx.x;
    const size_t off = ((size_t)bh * SEQ + s0) * HD;

    #pragma unroll
    for (int u = 0; u < 4; ++u) {                 // K: dense 16B loads, 8B stores
        int idx = u * 1024 + tid * 4;
        float4 a = *(const float4*)&K[off + idx];
        us4_t r4 = { f2bf(a.x), f2bf(a.y), f2bf(a.z), f2bf(a.w) };
        *(us4_t*)&Kb[off + idx] = r4;
    }
    #pragma unroll
    for (int u = 0; u < 4; ++u) {                 // V: dense loads -> padded LDS
        int idx = u * 1024 + tid * 4;
        int r = idx >> 6, col = idx & 63;
        float4 a = *(const float4*)&V[off + idx];
        *(unsigned int*)&T[r][col]     = pack2bf(a.x, a.y);
        *(unsigned int*)&T[r][col + 2] = pack2bf(a.z, a.w);
    }
    __syncthreads();
    unsigned short* Vdst = Vtb + (size_t)bh * HD * SEQ;
    const int g = tid & 7, dd = tid >> 3;         // dd 0..31
    #pragma unroll
    for (int h = 0; h < 2; ++h) {
        int d = dd + 32 * h;
        us8_t r8;
        #pragma unroll
        for (int j = 0; j < 8; ++j) r8[j] = T[g * 8 + j][d];
        *(us8_t*)&Vdst[(size_t)d * SEQ + s0 + g * 8] = r8;
    }
}

// ------------- main flash-attention kernel: barrier-free K-loop -------------
// TK=128 per iter; wave w owns n-quadrant [kv0+w*32,+32) over ALL 64 m.
// K/V fragments come straight from global (L2) with 1-iter register prefetch;
// no LDS staging, no __syncthreads in the loop. LDS: wave-private P only.
// Epilogue: barrier-sequenced 4-way O / lsum reduction.
__global__ __launch_bounds__(256)
void fa_main(const float* __restrict__ Q,
             const unsigned short* __restrict__ Kb,
             const unsigned short* __restrict__ Vtb,
             float* __restrict__ O, float qs) {
    const int x  = blockIdx.x & 7;
    const int t  = blockIdx.x >> 3;
    const int bh = x + 8 * (t % 3);
    const int qt = t / 3;
    const int q0 = qt * TQ;

    __shared__ __align__(16) unsigned char SHraw[18432];
    unsigned short* Qst   = (unsigned short*)SHraw;          // 8 KB Q staging
    float*          ORed  = (float*)SHraw;                   // [64 d][68] f32
    float*          Lpart = (float*)(SHraw + 17408);         // [4][64]

    const int tid  = threadIdx.x;
    const int w    = tid >> 6;
    const int lane = tid & 63;
    const int l31  = lane & 31;
    const int hi   = lane >> 5;

    const float*          Qh = Q   + ((size_t)bh * SEQ + q0) * HD;
    const unsigned short* Kh = Kb  + (size_t)bh * SEQ * HD;
    const unsigned short* Vh = Vtb + (size_t)bh * HD * SEQ;

    // per-lane global fragment bases (wave's n-quadrant)
    const unsigned short* Kq = Kh + (size_t)(w * 32 + l31) * HD + hi * 8;
    const unsigned short* Vq = Vh + (size_t)l31 * SEQ + w * 32 + hi * 8;

    // ---- issue tile-0 fragment loads first (land during Q staging) ----
    us8_t kc[4], vc[4];
    #pragma unroll
    for (int s = 0; s < 4; ++s) kc[s] = *(const us8_t*)&Kq[s * 16];
    #pragma unroll
    for (int dt = 0; dt < 2; ++dt)
        #pragma unroll
        for (int ks = 0; ks < 2; ++ks)
            vc[dt * 2 + ks] = *(const us8_t*)&Vq[(size_t)dt * 32 * SEQ + ks * 16];

    // ---- stage Q (fp32 -> scaled bf16), extract B-fragments, free LDS ----
    #pragma unroll
    for (int u = 0; u < 4; ++u) {
        int idx = u * 1024 + tid * 4;
        int r = idx >> 6, col = idx & 63;
        float4 a = *(const float4*)&Qh[idx];
        uint2 pk = { pack2bf(a.x * qs, a.y * qs), pack2bf(a.z * qs, a.w * qs) };
        *(uint2*)&Qst[tile_off(r, col >> 3) + (col & 7)] = pk;
    }
    __syncthreads();
    bf16x8 qf[2][4];
    #pragma unroll
    for (int mt = 0; mt < 2; ++mt)
        #pragma unroll
        for (int s = 0; s < 4; ++s)
            qf[mt][s] = *(const bf16x8*)&Qst[tile_off(mt * 32 + l31, s * 2 + hi)];
    __syncthreads();   // Q extracted; P regions may now overwrite

    unsigned short* Psw = (unsigned short*)SHraw + w * 2048;   // 4 KB/wave

    // hoisted wave-private P offsets
    int pWo[2][4], pRo[2][2];
    #pragma unroll
    for (int mt = 0; mt < 2; ++mt) {
        #pragma unroll
        for (int g = 0; g < 4; ++g)  pWo[mt][g]  = poff32(mt * 32 + l31, g) + hi * 4;
        #pragma unroll
        for (int ks = 0; ks < 2; ++ks) pRo[mt][ks] = poff32(mt * 32 + l31, ks * 2 + hi);
    }

    f32x16 o[2][2];
    o[0][0] = (f32x16)(0.f); o[0][1] = (f32x16)(0.f);
    o[1][0] = (f32x16)(0.f); o[1][1] = (f32x16)(0.f);
    float lsum[2] = {0.f, 0.f};

    #pragma unroll 2
    for (int it = 0; it < NITK; ++it) {
        // ---- prefetch next iteration's fragments (8 loads in flight) ----
        us8_t kn[4], vn[4];
        if (it + 1 < NITK) {
            const size_t ko = (size_t)(it + 1) * TKK * HD;
            const size_t vo = (size_t)(it + 1) * TKK;
            #pragma unroll
            for (int s = 0; s < 4; ++s) kn[s] = *(const us8_t*)&Kq[ko + s * 16];
            #pragma unroll
            for (int dt = 0; dt < 2; ++dt)
                #pragma unroll
                for (int ks = 0; ks < 2; ++ks)
                    vn[dt * 2 + ks] = *(const us8_t*)&Vq[vo + (size_t)dt * 32 * SEQ + ks * 16];
        }

        // ---- S^T quadrant = K(32n x 64d) . Q^T(64d x 64m): 2 indep chains ----
        f32x16 sc0 = (f32x16)(0.f), sc1 = (f32x16)(0.f);
        #pragma unroll
        for (int s = 0; s < 4; ++s) {
            bf16x8 kf = (bf16x8)kc[s];
            sc0 = __builtin_amdgcn_mfma_f32_32x32x16_bf16(kf, qf[0][s], sc0, 0, 0, 0);
            sc1 = __builtin_amdgcn_mfma_f32_32x32x16_bf16(kf, qf[1][s], sc1, 0, 0, 0);
        }

        // ---- exp2, lsum, P -> wave-private LDS (no barrier: same-wave RAW) ----
        #pragma unroll
        for (int mt = 0; mt < 2; ++mt) {
            const f32x16 s = mt ? sc1 : sc0;
            #pragma unroll
            for (int g = 0; g < 4; ++g) {
                float p0 = EXP2F(s[4*g+0]);
                float p1 = EXP2F(s[4*g+1]);
                float p2 = EXP2F(s[4*g+2]);
                float p3 = EXP2F(s[4*g+3]);
                lsum[mt] += (p0 + p1) + (p2 + p3);
                uint2 pk = { pack2bf(p0, p1), pack2bf(p2, p3) };
                *(uint2*)&Psw[pWo[mt][g]] = pk;
            }
        }

        // ---- PV: O[m][d] += P[m][n-quad] . V[n-quad][d]: 4 indep chains ----
        bf16x8 pf[2][2];
        #pragma unroll
        for (int mt = 0; mt < 2; ++mt)
            #pragma unroll
            for (int ks = 0; ks < 2; ++ks)
                pf[mt][ks] = *(const bf16x8*)&Psw[pRo[mt][ks]];
        #pragma unroll
        for (int dt = 0; dt < 2; ++dt)
            #pragma unroll
            for (int ks = 0; ks < 2; ++ks) {
                bf16x8 vf = (bf16x8)vc[dt * 2 + ks];
                o[0][dt] = __builtin_amdgcn_mfma_f32_32x32x16_bf16(pf[0][ks], vf, o[0][dt], 0, 0, 0);
                o[1][dt] = __builtin_amdgcn_mfma_f32_32x32x16_bf16(pf[1][ks], vf, o[1][dt], 0, 0, 0);
            }

        // rotate prefetch buffers (renamed away by unroll)
        #pragma unroll
        for (int s = 0; s < 4; ++s) { kc[s] = kn[s]; vc[s] = vn[s]; }
    }

    // ---- epilogue: lsum partials, then barrier-sequenced 4-way O reduce ----
    #pragma unroll
    for (int mt = 0; mt < 2; ++mt) lsum[mt] += __shfl_xor(lsum[mt], 32, 64);
    if (lane < 32) {
        Lpart[w * 64 + l31]      = lsum[0];
        Lpart[w * 64 + 32 + l31] = lsum[1];
    }

    #pragma unroll
    for (int rr = 0; rr < 4; ++rr) {
        __syncthreads();
        if (w == rr) {
            #pragma unroll
            for (int mt = 0; mt < 2; ++mt)
                #pragma unroll
                for (int dt = 0; dt < 2; ++dt) {
                    const int d = dt * 32 + l31;
                    #pragma unroll
                    for (int g = 0; g < 4; ++g) {
                        const int m0 = mt * 32 + 8 * g + 4 * hi;
                        float4 v = { o[mt][dt][4*g+0], o[mt][dt][4*g+1],
                                     o[mt][dt][4*g+2], o[mt][dt][4*g+3] };
                        if (rr != 0) {
                            float4 p = *(const float4*)&ORed[d * 68 + m0];
                            v.x += p.x; v.y += p.y; v.z += p.z; v.w += p.w;
                        }
                        *(float4*)&ORed[d * 68 + m0] = v;
                    }
                }
        }
    }
    __syncthreads();

    // ---- finalize: wave w covers m-rows [w*16, +16), lane = d (coalesced) ----
    float* Oh = O + ((size_t)bh * SEQ + q0) * HD;
    #pragma unroll
    for (int i = 0; i < 16; ++i) {
        const int m = w * 16 + i;
        float ltot = Lpart[m] + Lpart[64 + m] + Lpart[128 + m] + Lpart[192 + m];
        Oh[(size_t)m * HD + lane] = ORed[lane * 68 + m] * (1.0f / ltot);
    }
}

// ---------------- fallback (no-workspace) kernel ----------------
#define PAD 8
#define LSTR (HD + PAD)

__global__ __launch_bounds__(256)
void fa_fwd_fb(const float* __restrict__ Q, const float* __restrict__ K,
               const float* __restrict__ V, float* __restrict__ O) {
    const int x  = blockIdx.x & 7;
    const int t  = blockIdx.x >> 3;
    const int bh = x + 8 * (t % 3);
    const int qt = t / 3;
    const int q0 = qt * TQ;
    const long base = (long)bh * SEQ * HD;

    __shared__ unsigned short Qs[TQ][LSTR];
    __shared__ unsigned short Ks2[64][LSTR];
    __shared__ unsigned short Vt[HD][64 + PAD];
    __shared__ unsigned short Ps2[4][16][LSTR];

    const int tid  = threadIdx.x;
    const int wave = tid >> 6;
    const int lane = tid & 63;
    const int col  = lane & 15;
    const int quad = lane >> 4;
    const int m0   = wave * 16;

    #pragma unroll
    for (int i = 0; i < 4; ++i) {
        int idx = tid + 256 * i;
        int row = idx >> 4;
        int c4  = (idx & 15) * 4;
        float4 v = *(const float4*)&Q[base + (long)(q0 + row) * HD + c4];
        ushort4 b = { f2bf(v.x), f2bf(v.y), f2bf(v.z), f2bf(v.w) };
        *(ushort4*)&Qs[row][c4] = b;
    }
    __syncthreads();

    bf16x8 aq0 = *(const bf16x8*)&Qs[m0 + col][quad * 8];
    bf16x8 aq1 = *(const bf16x8*)&Qs[m0 + col][32 + quad * 8];

    f32x4 o0 = {0.f,0.f,0.f,0.f}, o1 = o0, o2 = o0, o3 = o0;
    float l[4] = {0.f, 0.f, 0.f, 0.f};
    const float scale = 0.022097086912079608f;

    for (int kv0 = 0; kv0 < SEQ; kv0 += 64) {
        __syncthreads();
        #pragma unroll
        for (int i = 0; i < 4; ++i) {
            int idx = tid + 256 * i;
            int row = idx >> 4;
            int c4  = (idx & 15) * 4;
            float4 kv = *(const float4*)&K[base + (long)(kv0 + row) * HD + c4];
            ushort4 kb = { f2bf(kv.x), f2bf(kv.y), f2bf(kv.z), f2bf(kv.w) };
            *(ushort4*)&Ks2[row][c4] = kb;
            float4 vv = *(const float4*)&V[base + (long)(kv0 + row) * HD + c4];
            Vt[c4 + 0][row] = f2bf(vv.x);
            Vt[c4 + 1][row] = f2bf(vv.y);
            Vt[c4 + 2][row] = f2bf(vv.z);
            Vt[c4 + 3][row] = f2bf(vv.w);
        }
        __syncthreads();

        f32x4 sc[4];
        #pragma unroll
        for (int n = 0; n < 4; ++n) {
            bf16x8 b0 = *(const bf16x8*)&Ks2[n * 16 + col][quad * 8];
            bf16x8 b1 = *(const bf16x8*)&Ks2[n * 16 + col][32 + quad * 8];
            f32x4 acc = {0.f,0.f,0.f,0.f};
            acc = __builtin_amdgcn_mfma_f32_16x16x32_bf16(aq0, b0, acc, 0, 0, 0);
            acc = __builtin_amdgcn_mfma_f32_16x16x32_bf16(aq1, b1, acc, 0, 0, 0);
            sc[n] = acc;
        }

        float tsum[4] = {0.f, 0.f, 0.f, 0.f};
        #pragma unroll
        for (int n = 0; n < 4; ++n) {
            #pragma unroll
            for (int r = 0; r < 4; ++r) {
                float p = __expf(sc[n][r] * scale);
                tsum[r] += p;
                Ps2[wave][quad * 4 + r][n * 16 + col] = f2bf(p);
            }
        }
        #pragma unroll
        for (int off = 1; off < 16; off <<= 1) {
            #pragma unroll
            for (int r = 0; r < 4; ++r) tsum[r] += __shfl_xor(tsum[r], off, 64);
        }
        #pragma unroll
        for (int r = 0; r < 4; ++r) l[r] += tsum[r];

        bf16x8 ap0 = *(const bf16x8*)&Ps2[wave][col][quad * 8];
        bf16x8 ap1 = *(const bf16x8*)&Ps2[wave][col][32 + quad * 8];
        #pragma unroll
        for (int n = 0; n < 4; ++n) {
            bf16x8 b0 = *(const bf16x8*)&Vt[n * 16 + col][quad * 8];
            bf16x8 b1 = *(const bf16x8*)&Vt[n * 16 + col][32 + quad * 8];
            f32x4* op = (n == 0) ? &o0 : (n == 1) ? &o1 : (n == 2) ? &o2 : &o3;
            *op = __builtin_amdgcn_mfma_f32_16x16x32_bf16(ap0, b0, *op, 0, 0, 0);
            *op = __builtin_amdgcn_mfma_f32_16x16x32_bf16(ap1, b1, *op, 0, 0, 0);
        }
    }

    float inv[4];
    #pragma unroll
    for (int r = 0; r < 4; ++r) inv[r] = 1.0f / l[r];
    #pragma unroll
    for (int r = 0; r < 4; ++r) {
        long row = base + (long)(q0 + m0 + quad * 4 + r) * HD;
        O[row +  0 + col] = o0[r] * inv[r];
        O[row + 16 + col] = o1[r] * inv[r];
        O[row + 32 + col] = o2[r] * inv[r];
        O[row + 48 + col] = o3[r] * inv[r];
    }
}

extern "C" void kernel_launch(void* const* d_in, const int* in_sizes, int n_in,
                              void* d_out, int out_size, void* d_ws, size_t ws_size,
                              hipStream_t stream) {
    const float* Q = (const float*)d_in[0];
    const float* K = (const float*)d_in[1];
    const float* V = (const float*)d_in[2];
    float* O = (float*)d_out;

    const size_t tensorElems = (size_t)NHEADS * SEQ * HD;
    const size_t need = 2 * tensorElems * sizeof(unsigned short);

    if (ws_size >= need) {
        unsigned short* Kb  = (unsigned short*)d_ws;
        unsigned short* Vtb = Kb + tensorElems;
        const float qs = (float)(1.4426950408889634 / sqrt(2048.0));  // log2e/sqrt(S)
        prep_kv<<<dim3(NHEADS * (SEQ / 64)), dim3(256), 0, stream>>>(K, V, Kb, Vtb);
        fa_main<<<dim3(NHEADS * (SEQ / TQ)), dim3(256), 0, stream>>>(Q, Kb, Vtb, O, qs);
    } else {
        fa_fwd_fb<<<dim3(NHEADS * (SEQ / TQ)), dim3(256), 0, stream>>>(Q, K, V, O);
    }
}

// Round 8
// 117.692 us; speedup vs baseline: 1.1530x; 1.1530x over previous
//
#include <hip/hip_runtime.h>
#include <hip/hip_bf16.h>
#include <math.h>
#include <stdint.h>

#define BATCH 2
#define NH 12
#define SEQ 2048
#define HD 64
#define TQ 64
#define TK 64
#define NHEADS (BATCH*NH)
#define NIT (SEQ / TK)

typedef short bf16x8 __attribute__((ext_vector_type(8)));
typedef float f32x4 __attribute__((ext_vector_type(4)));
typedef float f32x16 __attribute__((ext_vector_type(16)));
typedef unsigned short us4_t __attribute__((ext_vector_type(4)));
typedef unsigned short us8_t __attribute__((ext_vector_type(8)));
typedef unsigned int u32x4 __attribute__((ext_vector_type(4)));

#if __has_builtin(__builtin_amdgcn_exp2f)
#define EXP2F(x) __builtin_amdgcn_exp2f(x)
#else
#define EXP2F(x) exp2f(x)
#endif

static __device__ __forceinline__ unsigned short f2bf(float f) {
    unsigned int u = __float_as_uint(f);
    u += 0x7fffu + ((u >> 16) & 1u);   // RTNE
    return (unsigned short)(u >> 16);
}

static __device__ __forceinline__ unsigned int pack2bf(float a, float b) {
    __hip_bfloat162 v = __float22bfloat162_rn(float2{a, b});
    return *(unsigned int*)&v;          // low short = a
}

static __device__ __forceinline__ void async_cp16(const void* g, void* l) {
    __builtin_amdgcn_global_load_lds(
        (const __attribute__((address_space(1))) void*)g,
        (__attribute__((address_space(3))) void*)(uintptr_t)l,
        16, 0, 0);
}

// Conflict-free 64x64-bf16 tile layout: 32 row-pairs x 256B, 16 positions of
// 16B, pos = ((r&1)*8 | c) ^ ((r>>1)&15).
static __device__ __forceinline__ int tile_off(int r, int c) {   // shorts, c 0..7
    int rp  = r >> 1;
    int pos = (((r & 1) << 3) | c) ^ (rp & 15);
    return rp * 128 + pos * 8;
}

// ---- pre-pass: K -> bf16 (dense), V -> bf16 transposed [bh][d][s'] where
// s' = s with bits 2<->3 swapped inside each 32-block (pi-permutation that
// makes the S^T C-layout register order equal the PV A-operand order).
__global__ __launch_bounds__(256)
void prep_kv(const float* __restrict__ K, const float* __restrict__ V,
             unsigned short* __restrict__ Kb, unsigned short* __restrict__ Vtb) {
    __shared__ unsigned short T[64][66];
    const int bh = blockIdx.x >> 5;
    const int s0 = (blockIdx.x & 31) * 64;
    const int tid = threadIdx.x;
    const size_t off = ((size_t)bh * SEQ + s0) * HD;

    #pragma unroll
    for (int u = 0; u < 4; ++u) {                 // K: dense 16B loads, 8B stores
        int idx = u * 1024 + tid * 4;
        float4 a = *(const float4*)&K[off + idx];
        us4_t r4 = { f2bf(a.x), f2bf(a.y), f2bf(a.z), f2bf(a.w) };
        *(us4_t*)&Kb[off + idx] = r4;
    }
    #pragma unroll
    for (int u = 0; u < 4; ++u) {                 // V: dense loads -> padded LDS
        int idx = u * 1024 + tid * 4;
        int r = idx >> 6, col = idx & 63;
        float4 a = *(const float4*)&V[off + idx];
        *(unsigned int*)&T[r][col]     = pack2bf(a.x, a.y);
        *(unsigned int*)&T[r][col + 2] = pack2bf(a.z, a.w);
    }
    __syncthreads();
    unsigned short* Vdst = Vtb + (size_t)bh * HD * SEQ;
    const int g = tid & 7, dd = tid >> 3;         // dd 0..31
    #pragma unroll
    for (int h = 0; h < 2; ++h) {
        int d = dd + 32 * h;
        us8_t r8;
        #pragma unroll
        for (int j = 0; j < 8; ++j) {
            // pi: swap bits 2,3 of the 64-local column index (g*8 + j)
            int src = ((g >> 1) << 4) + ((j >> 2) << 3) + ((g & 1) << 2) + (j & 3);
            r8[j] = T[src][d];
        }
        *(us8_t*)&Vdst[(size_t)d * SEQ + s0 + g * 8] = r8;
    }
}

// ---------------- main flash-attention kernel (32x32x16 MFMA) ----------------
// R6 structure (double-buffered async K/V staging, wave (mt,nt) owns S^T
// quadrant, 1 barrier/iter) but the P round-trip is GONE: V rows are
// pi-permuted in global memory, so the PV A-fragment is the exp'd score
// registers packed in order. LDS = 33 KB -> 4 blocks/CU.
__global__ __launch_bounds__(256, 4)
void fa_main(const float* __restrict__ Q,
             const unsigned short* __restrict__ Kb,
             const unsigned short* __restrict__ Vtb,
             float* __restrict__ O, float qs) {
    const int x  = blockIdx.x & 7;
    const int t  = blockIdx.x >> 3;
    const int bh = x + 8 * (t % 3);
    const int qt = t / 3;
    const int q0 = qt * TQ;

    __shared__ __align__(16) unsigned char SH[33280];
    unsigned short* Ksh0 = (unsigned short*)SH;            // 8 KB
    unsigned short* Ksh1 = (unsigned short*)(SH + 8192);   // 8 KB
    unsigned short* Vsh0 = (unsigned short*)(SH + 16384);  // 8 KB
    unsigned short* Vsh1 = (unsigned short*)(SH + 24576);  // 8 KB (Q staging union)
    float* Lsum = (float*)(SH + 32768);                    // 64
    float* Linv = (float*)(SH + 33024);                    // 64
    float* ORed = (float*)SH;                              // 64 x 68 f32 overlay

    const int tid  = threadIdx.x;
    const int w    = tid >> 6;
    const int mt   = w >> 1;
    const int nt   = w & 1;
    const int lane = tid & 63;
    const int l31  = lane & 31;
    const int hi   = lane >> 5;

    const float*          Qh = Q   + ((size_t)bh * SEQ + q0) * HD;
    const unsigned short* Kh = Kb  + (size_t)bh * SEQ * HD;
    const unsigned short* Vh = Vtb + (size_t)bh * HD * SEQ;

    // ---- per-lane staging source offsets (loop-invariant, R6 pattern) ----
    int rS[2], cS[2];
    #pragma unroll
    for (int i = 0; i < 2; ++i) {
        int rp = w * 8 + 4 * i + (lane >> 4);
        int lc = (lane & 15) ^ (rp & 15);
        rS[i] = 2 * rp + (lc >> 3);
        cS[i] = lc & 7;
    }
    const int dst0 = (w * 8 + 0) * 128, dst1 = (w * 8 + 4) * 128;  // shorts
    const size_t kG0 = (size_t)rS[0] * HD  + cS[0] * 8;
    const size_t kG1 = (size_t)rS[1] * HD  + cS[1] * 8;
    const size_t vG0 = (size_t)rS[0] * SEQ + cS[0] * 8;
    const size_t vG1 = (size_t)rS[1] * SEQ + cS[1] * 8;

    // ---- prologue: K/V tile 0 -> buf0 (async); Q (fp32 -> scaled bf16) -> Vsh1
    async_cp16(Kh + kG0, &Ksh0[dst0]);
    async_cp16(Kh + kG1, &Ksh0[dst1]);
    async_cp16(Vh + vG0, &Vsh0[dst0]);
    async_cp16(Vh + vG1, &Vsh0[dst1]);
    #pragma unroll
    for (int u = 0; u < 4; ++u) {
        int idx = u * 1024 + tid * 4;
        int r = idx >> 6, col = idx & 63;
        float4 a = *(const float4*)&Qh[idx];
        uint2 pk = { pack2bf(a.x * qs, a.y * qs), pack2bf(a.z * qs, a.w * qs) };
        *(uint2*)&Vsh1[tile_off(r, col >> 3) + (col & 7)] = pk;
    }
    __syncthreads();   // Q staged + tile 0 resident

    // ---- Q B-fragments (rows mt*32..+32) -> registers; then Vsh1 is free ----
    bf16x8 qf[4];
    #pragma unroll
    for (int s = 0; s < 4; ++s)
        qf[s] = *(const bf16x8*)&Vsh1[tile_off(mt * 32 + l31, s * 2 + hi)];
    __syncthreads();   // everyone extracted Q before tile-1 prefetch overwrites

    // ---- hoisted fragment LDS offsets ----
    int kOffL[4], vOffL[2][2];
    #pragma unroll
    for (int s = 0; s < 4; ++s) kOffL[s] = tile_off(nt * 32 + l31, s * 2 + hi);
    #pragma unroll
    for (int dt = 0; dt < 2; ++dt)
        #pragma unroll
        for (int ks = 0; ks < 2; ++ks)
            vOffL[dt][ks] = tile_off(dt * 32 + l31, nt * 4 + ks * 2 + hi);

    f32x16 o[2];
    o[0] = (f32x16)(0.f);
    o[1] = (f32x16)(0.f);
    float lsum = 0.f;

    #pragma unroll 2
    for (int it = 0; it < NIT; ++it) {
        const int cur = it & 1;
        if (it + 1 < NIT) {            // prefetch next tile into other buffer
            const size_t kv = (size_t)(it + 1) * TK;
            unsigned short* Kn = cur ? Ksh0 : Ksh1;
            unsigned short* Vn = cur ? Vsh0 : Vsh1;
            async_cp16(Kh + kv * HD + kG0, &Kn[dst0]);
            async_cp16(Kh + kv * HD + kG1, &Kn[dst1]);
            async_cp16(Vh + kv + vG0,      &Vn[dst0]);
            async_cp16(Vh + kv + vG1,      &Vn[dst1]);
        }
        const unsigned short* Ks = cur ? Ksh1 : Ksh0;
        const unsigned short* Vs = cur ? Vsh1 : Vsh0;

        // ---- issue V-fragment reads early (independent of QK chain) ----
        bf16x8 vf[2][2];
        #pragma unroll
        for (int dt = 0; dt < 2; ++dt)
            #pragma unroll
            for (int ks = 0; ks < 2; ++ks)
                vf[dt][ks] = *(const bf16x8*)&Vs[vOffL[dt][ks]];

        // ---- S^T quadrant = K(32x64) . Q^T(64x32): 4 MFMAs ----
        f32x16 sc = (f32x16)(0.f);
        #pragma unroll
        for (int s = 0; s < 4; ++s) {
            bf16x8 kf = *(const bf16x8*)&Ks[kOffL[s]];
            sc = __builtin_amdgcn_mfma_f32_32x32x16_bf16(kf, qf[s], sc, 0, 0, 0);
        }

        // ---- exp2 + lsum; pack A-fragments directly from registers ----
        float e[16];
        #pragma unroll
        for (int r = 0; r < 16; ++r) e[r] = EXP2F(sc[r]);
        #pragma unroll
        for (int r = 0; r < 16; ++r) lsum += e[r];
        union { u32x4 d; bf16x8 h; } pu0, pu1;
        pu0.d = (u32x4){ pack2bf(e[0],  e[1]),  pack2bf(e[2],  e[3]),
                         pack2bf(e[4],  e[5]),  pack2bf(e[6],  e[7]) };
        pu1.d = (u32x4){ pack2bf(e[8],  e[9]),  pack2bf(e[10], e[11]),
                         pack2bf(e[12], e[13]), pack2bf(e[14], e[15]) };
        bf16x8 pf0 = pu0.h, pf1 = pu1.h;

        // ---- PV partial: O[m][d] += P[m][n-half] . V[n-half][d]: 4 MFMAs ----
        #pragma unroll
        for (int dt = 0; dt < 2; ++dt) {
            o[dt] = __builtin_amdgcn_mfma_f32_32x32x16_bf16(pf0, vf[dt][0], o[dt], 0, 0, 0);
            o[dt] = __builtin_amdgcn_mfma_f32_32x32x16_bf16(pf1, vf[dt][1], o[dt], 0, 0, 0);
        }

        __syncthreads();   // reads of buf[cur] done; prefetch drained
    }

    // ---- epilogue: combine nt partials (O and lsum), normalize, store ----
    lsum += __shfl_xor(lsum, 32, 64);

    if (nt == 1) {
        if (lane < 32) Lsum[mt * 32 + lane] = lsum;
        #pragma unroll
        for (int dt = 0; dt < 2; ++dt) {
            const int d = dt * 32 + l31;
            #pragma unroll
            for (int g = 0; g < 4; ++g) {
                const int m0 = mt * 32 + 8 * g + 4 * hi;
                const int ph = (m0 >> 2) ^ (d & 15);
                float4 v = { o[dt][4*g+0], o[dt][4*g+1], o[dt][4*g+2], o[dt][4*g+3] };
                *(float4*)&ORed[d * 64 + ph * 4] = v;
            }
        }
    }
    __syncthreads();

    if (nt == 0) {
        float ltot = lsum + Lsum[mt * 32 + l31];
        if (lane < 32) Linv[mt * 32 + lane] = 1.0f / ltot;
        float* Oh = O + ((size_t)bh * SEQ + q0) * HD;
        #pragma unroll
        for (int dt = 0; dt < 2; ++dt) {
            const int d = dt * 32 + l31;
            #pragma unroll
            for (int g = 0; g < 4; ++g) {
                const int m0 = mt * 32 + 8 * g + 4 * hi;
                const int ph = (m0 >> 2) ^ (d & 15);
                float4 part = *(const float4*)&ORed[d * 64 + ph * 4];
                float4 inv4 = *(const float4*)&Linv[m0];
                const float* pp = (const float*)&part;
                const float* ii = (const float*)&inv4;
                #pragma unroll
                for (int j = 0; j < 4; ++j)
                    Oh[(size_t)(m0 + j) * HD + d] = (o[dt][4*g+j] + pp[j]) * ii[j];
            }
        }
    }
}

// ---------------- fallback (no-workspace) kernel ----------------
#define PAD 8
#define LSTR (HD + PAD)

__global__ __launch_bounds__(256)
void fa_fwd_fb(const float* __restrict__ Q, const float* __restrict__ K,
               const float* __restrict__ V, float* __restrict__ O) {
    const int x  = blockIdx.x & 7;
    const int t  = blockIdx.x >> 3;
    const int bh = x + 8 * (t % 3);
    const int qt = t / 3;
    const int q0 = qt * TQ;
    const long base = (long)bh * SEQ * HD;

    __shared__ unsigned short Qs[TQ][LSTR];
    __shared__ unsigned short Ks2[64][LSTR];
    __shared__ unsigned short Vt[HD][64 + PAD];
    __shared__ unsigned short Ps2[4][16][LSTR];

    const int tid  = threadIdx.x;
    const int wave = tid >> 6;
    const int lane = tid & 63;
    const int col  = lane & 15;
    const int quad = lane >> 4;
    const int m0   = wave * 16;

    #pragma unroll
    for (int i = 0; i < 4; ++i) {
        int idx = tid + 256 * i;
        int row = idx >> 4;
        int c4  = (idx & 15) * 4;
        float4 v = *(const float4*)&Q[base + (long)(q0 + row) * HD + c4];
        ushort4 b = { f2bf(v.x), f2bf(v.y), f2bf(v.z), f2bf(v.w) };
        *(ushort4*)&Qs[row][c4] = b;
    }
    __syncthreads();

    bf16x8 aq0 = *(const bf16x8*)&Qs[m0 + col][quad * 8];
    bf16x8 aq1 = *(const bf16x8*)&Qs[m0 + col][32 + quad * 8];

    f32x4 o0 = {0.f,0.f,0.f,0.f}, o1 = o0, o2 = o0, o3 = o0;
    float l[4] = {0.f, 0.f, 0.f, 0.f};
    const float scale = 0.022097086912079608f;

    for (int kv0 = 0; kv0 < SEQ; kv0 += 64) {
        __syncthreads();
        #pragma unroll
        for (int i = 0; i < 4; ++i) {
            int idx = tid + 256 * i;
            int row = idx >> 4;
            int c4  = (idx & 15) * 4;
            float4 kv = *(const float4*)&K[base + (long)(kv0 + row) * HD + c4];
            ushort4 kb = { f2bf(kv.x), f2bf(kv.y), f2bf(kv.z), f2bf(kv.w) };
            *(ushort4*)&Ks2[row][c4] = kb;
            float4 vv = *(const float4*)&V[base + (long)(kv0 + row) * HD + c4];
            Vt[c4 + 0][row] = f2bf(vv.x);
            Vt[c4 + 1][row] = f2bf(vv.y);
            Vt[c4 + 2][row] = f2bf(vv.z);
            Vt[c4 + 3][row] = f2bf(vv.w);
        }
        __syncthreads();

        f32x4 sc[4];
        #pragma unroll
        for (int n = 0; n < 4; ++n) {
            bf16x8 b0 = *(const bf16x8*)&Ks2[n * 16 + col][quad * 8];
            bf16x8 b1 = *(const bf16x8*)&Ks2[n * 16 + col][32 + quad * 8];
            f32x4 acc = {0.f,0.f,0.f,0.f};
            acc = __builtin_amdgcn_mfma_f32_16x16x32_bf16(aq0, b0, acc, 0, 0, 0);
            acc = __builtin_amdgcn_mfma_f32_16x16x32_bf16(aq1, b1, acc, 0, 0, 0);
            sc[n] = acc;
        }

        float tsum[4] = {0.f, 0.f, 0.f, 0.f};
        #pragma unroll
        for (int n = 0; n < 4; ++n) {
            #pragma unroll
            for (int r = 0; r < 4; ++r) {
                float p = __expf(sc[n][r] * scale);
                tsum[r] += p;
                Ps2[wave][quad * 4 + r][n * 16 + col] = f2bf(p);
            }
        }
        #pragma unroll
        for (int off = 1; off < 16; off <<= 1) {
            #pragma unroll
            for (int r = 0; r < 4; ++r) tsum[r] += __shfl_xor(tsum[r], off, 64);
        }
        #pragma unroll
        for (int r = 0; r < 4; ++r) l[r] += tsum[r];

        bf16x8 ap0 = *(const bf16x8*)&Ps2[wave][col][quad * 8];
        bf16x8 ap1 = *(const bf16x8*)&Ps2[wave][col][32 + quad * 8];
        #pragma unroll
        for (int n = 0; n < 4; ++n) {
            bf16x8 b0 = *(const bf16x8*)&Vt[n * 16 + col][quad * 8];
            bf16x8 b1 = *(const bf16x8*)&Vt[n * 16 + col][32 + quad * 8];
            f32x4* op = (n == 0) ? &o0 : (n == 1) ? &o1 : (n == 2) ? &o2 : &o3;
            *op = __builtin_amdgcn_mfma_f32_16x16x32_bf16(ap0, b0, *op, 0, 0, 0);
            *op = __builtin_amdgcn_mfma_f32_16x16x32_bf16(ap1, b1, *op, 0, 0, 0);
        }
    }

    float inv[4];
    #pragma unroll
    for (int r = 0; r < 4; ++r) inv[r] = 1.0f / l[r];
    #pragma unroll
    for (int r = 0; r < 4; ++r) {
        long row = base + (long)(q0 + m0 + quad * 4 + r) * HD;
        O[row +  0 + col] = o0[r] * inv[r];
        O[row + 16 + col] = o1[r] * inv[r];
        O[row + 32 + col] = o2[r] * inv[r];
        O[row + 48 + col] = o3[r] * inv[r];
    }
}

extern "C" void kernel_launch(void* const* d_in, const int* in_sizes, int n_in,
                              void* d_out, int out_size, void* d_ws, size_t ws_size,
                              hipStream_t stream) {
    const float* Q = (const float*)d_in[0];
    const float* K = (const float*)d_in[1];
    const float* V = (const float*)d_in[2];
    float* O = (float*)d_out;

    const size_t tensorElems = (size_t)NHEADS * SEQ * HD;
    const size_t need = 2 * tensorElems * sizeof(unsigned short);

    if (ws_size >= need) {
        unsigned short* Kb  = (unsigned short*)d_ws;
        unsigned short* Vtb = Kb + tensorElems;
        const float qs = (float)(1.4426950408889634 / sqrt(2048.0));  // log2e/sqrt(S)
        prep_kv<<<dim3(NHEADS * (SEQ / 64)), dim3(256), 0, stream>>>(K, V, Kb, Vtb);
        fa_main<<<dim3(NHEADS * (SEQ / TQ)), dim3(256), 0, stream>>>(Q, Kb, Vtb, O, qs);
    } else {
        fa_fwd_fb<<<dim3(NHEADS * (SEQ / TQ)), dim3(256), 0, stream>>>(Q, K, V, O);
    }
}